// Round 23
// baseline (76.387 us; speedup 1.0000x reference)
//
#include <hip/hip_runtime.h>
#include <hip/hip_bf16.h>

#define CIN  64
#define HH   128
#define WW   128
#define COUT 128
#define HO   126
#define WO   126
#define NB   32
#define HW   (HH * WW)

typedef __bf16 bf16x8 __attribute__((ext_vector_type(8)));
typedef float f32x4 __attribute__((ext_vector_type(4)));

// ws2 granule layout: [step(18)=(s,h)][kg(4)][cout(128)] 16B granules
// granule(step,kg,cout)[j] = bf16(w[cout][ci = 32h + 8kg + j][s])
__global__ void wreorder_3556(const float* __restrict__ w, unsigned short* __restrict__ ws2) {
    int e = blockIdx.x * 256 + threadIdx.x;      // 0..73727
    if (e >= 73728) return;
    int j = e & 7, cout = (e >> 3) & 127, kg = (e >> 10) & 3, h = (e >> 12) & 1, s = e >> 13;
    __bf16 v = (__bf16)w[cout * 576 + (h * 32 + kg * 8 + j) * 9 + s];
    ws2[e] = __builtin_bit_cast(unsigned short, v);
}

// LDS x layout: [row(3)][h(2)][blk(8)][kg(4)][c(16)] 16B granules, contiguous (no pad, no block 8)
//   addr(row,h,col,kg) = row*16384 + h*8192 + (col>>4)*1024 + kg*256 + (col&15)*16
// Carry reads (col>=128) land in adjacent region/pmin: garbage -> only discarded cols 126/127.
#define ROW_STRIDE 16384
#define H_STRIDE   8192
#define PM_OFF     49152
#define SMEM_BYTES (49152 + 1024)   // 50176 -> 3 blocks/CU

__device__ __forceinline__ unsigned lds_addr(const void* p) {
    return (unsigned)(unsigned long long)(const __attribute__((address_space(3))) unsigned char*)p;
}
template<int OFF>
__device__ __forceinline__ bf16x8 ds_read128(unsigned base) {
    bf16x8 d;
    asm volatile("ds_read_b128 %0, %1 offset:%c2" : "=v"(d) : "v"(base), "i"(OFF));
    return d;
}
template<int OFF>
__device__ __forceinline__ bf16x8 glob_load128(const unsigned char* sbase, unsigned voff) {
    bf16x8 d;
    asm volatile("global_load_dwordx4 %0, %1, %2 offset:%c3"
                 : "=v"(d) : "v"(voff), "s"(sbase), "i"(OFF));
    return d;
}

#define MFMA16_(a, b, c) __builtin_amdgcn_mfma_f32_16x16x32_bf16((a), (b), (c), 0, 0, 0)
#define SBAR() __builtin_amdgcn_sched_barrier(0)

// step T: s = T>>1, h = T&1; kh = s/3, kw = s%3
#define S_(T)  ((T) >> 1)
#define H_(T)  ((T) & 1)
#define KH_(T) (S_(T) / 3)
#define KW_(T) (S_(T) % 3)
#define IMMB(T, N) (KH_(T) * ROW_STRIDE + H_(T) * H_STRIDE + (N) * 1024)

template<bool USE_WS>
__global__ __launch_bounds__(256, 3)
void conv_min_tanh_3556(const float* __restrict__ x, const float* __restrict__ w,
                        const float* __restrict__ bias,
                        const unsigned char* __restrict__ wsr_b,
                        float* __restrict__ out) {
    __shared__ __align__(16) unsigned char smem[SMEM_BYTES];
    float* pmin = (float*)(smem + PM_OFF);

    // XCD-chunked bijective swizzle (4032 = 8 * 504)
    const int bid = blockIdx.x;
    const int blk = (bid & 7) * 504 + (bid >> 3);
    const int b   = blk / HO;
    const int R   = blk - b * HO;            // output row; input rows R..R+2 (always in-bounds)

    const int tid  = threadIdx.x;
    const int lane = tid & 63;
    const int wid  = tid >> 6;               // 0..3
    const int l15 = lane & 15;
    const int lg  = lane >> 4;               // 0..3 (16-lane group)
    const int waveM = wid & 1;               // cout half (0/1)
    const int waveC = wid >> 1;              // col half (0/1)
    const int mb = waveM * 64;

    // ---- A register pipeline + early prefetch (hidden under staging)
    bf16x8 A2[2][4];   // [slot][m]  32 VGPR
    bf16x8 B2[2][4];   // [slot][n]  32 VGPR
    const unsigned voffA = (unsigned)(lg * 2048 + (mb + l15) * 16);

    #define PRELA(T) do { const unsigned _va = voffA + (T) * 8192u;                       \
        A2[(T) & 1][0] = glob_load128<0>(wsr_b, _va);                                     \
        A2[(T) & 1][1] = glob_load128<256>(wsr_b, _va);                                   \
        A2[(T) & 1][2] = glob_load128<512>(wsr_b, _va);                                   \
        A2[(T) & 1][3] = glob_load128<768>(wsr_b, _va); } while (0)

    if constexpr (USE_WS) { PRELA(0); PRELA(1); }

    // ---- stage x rows R..R+2 (768 items, 3/thread), vectorized f32x4, block-16-col layout
    {
        const float* xb = x + (size_t)b * CIN * HW + (size_t)R * WW;
        #pragma unroll
        for (int it = 0; it < 3; ++it) {
            int item = it * 256 + tid;          // 0..767
            int col4 = item & 31;               // 4-col group
            int cg   = (item >> 5) & 7;         // h = cg>>2, kg = cg&3
            int row  = item >> 8;               // 0..2
            const float* src = xb + (size_t)(cg * 8) * HW + (size_t)row * WW + col4 * 4;
            f32x4 v[8];
            #pragma unroll
            for (int j = 0; j < 8; ++j) v[j] = *(const f32x4*)(src + (size_t)j * HW);
            const int wb0 = row * ROW_STRIDE + (cg >> 2) * H_STRIDE + (cg & 3) * 256;
            #pragma unroll
            for (int c = 0; c < 4; ++c) {
                int col = col4 * 4 + c;
                union { unsigned short us[8]; int4 i4; } p;
                #pragma unroll
                for (int j = 0; j < 8; ++j) {
                    __bf16 t = (__bf16)v[j][c];
                    p.us[j] = __builtin_bit_cast(unsigned short, t);
                }
                *(int4*)(smem + wb0 + (col >> 4) * 1024 + (col & 15) * 16) = p.i4;
            }
        }
    }
    __syncthreads();   // drains vmcnt: A2 slots 0,1 resident; xs ready

    f32x4 acc[4][4] = {};   // [m][n] : 64 cout x 64 col, 16x16 tiles

    if constexpr (USE_WS) {
        // B bases per kw: col' = waveC*64 + l15 + kw (waveC*4 blocks folded into base)
        unsigned baseB[3];
        #pragma unroll
        for (int kw = 0; kw < 3; ++kw) {
            int cp = l15 + kw;
            baseB[kw] = lds_addr(smem) + (unsigned)(waveC * 4096 + lg * 256 +
                        (cp >> 4) * 1024 + (cp & 15) * 16);
        }

        #define PRELB(T) do { const unsigned _bb = baseB[KW_(T)];                         \
            B2[(T) & 1][0] = ds_read128<IMMB(T,0)>(_bb);                                  \
            B2[(T) & 1][1] = ds_read128<IMMB(T,1)>(_bb);                                  \
            B2[(T) & 1][2] = ds_read128<IMMB(T,2)>(_bb);                                  \
            B2[(T) & 1][3] = ds_read128<IMMB(T,3)>(_bb); } while (0)

        #define KSTEP(T) do {                                                             \
            if ((T) <= 16) asm volatile("s_waitcnt lgkmcnt(4) vmcnt(4)" ::: "memory");    \
            else           asm volatile("s_waitcnt lgkmcnt(0) vmcnt(0)" ::: "memory");    \
            SBAR();                                                                       \
            __builtin_amdgcn_s_setprio(1);                                                \
            { const int _q = (T) & 1;                                                     \
              _Pragma("unroll")                                                           \
              for (int _m = 0; _m < 4; ++_m)                                              \
                _Pragma("unroll")                                                         \
                for (int _n = 0; _n < 4; ++_n)                                            \
                    acc[_m][_n] = MFMA16_(A2[_q][_m], B2[_q][_n], acc[_m][_n]); }         \
            __builtin_amdgcn_s_setprio(0);                                                \
            SBAR();                                                                       \
            if ((T) + 2 <= 17) { PRELB((T) + 2); PRELA((T) + 2); }                        \
        } while (0)

        PRELB(0); PRELB(1);

        KSTEP(0);  KSTEP(1);  KSTEP(2);  KSTEP(3);  KSTEP(4);  KSTEP(5);
        KSTEP(6);  KSTEP(7);  KSTEP(8);  KSTEP(9);  KSTEP(10); KSTEP(11);
        KSTEP(12); KSTEP(13); KSTEP(14); KSTEP(15); KSTEP(16); KSTEP(17);

        asm volatile("s_waitcnt lgkmcnt(0) vmcnt(0)" ::: "memory");
        SBAR();
    } else {
        // fallback: plain 18-step loop straight from w
        #pragma unroll
        for (int step = 0; step < 18; ++step) {
            const int s = step >> 1, h = step & 1;
            const int kh = s / 3, kw = s % 3;
            bf16x8 A[4], B[4];
            #pragma unroll
            for (int m = 0; m < 4; ++m)
                #pragma unroll
                for (int j = 0; j < 8; ++j)
                    A[m][j] = (__bf16)w[(mb + m * 16 + l15) * 576 +
                                        (h * 32 + lg * 8 + j) * 9 + s];
            #pragma unroll
            for (int n = 0; n < 4; ++n) {
                int col = waveC * 64 + n * 16 + l15 + kw;
                B[n] = *(const bf16x8*)(smem + kh * ROW_STRIDE + h * H_STRIDE +
                                        (col >> 4) * 1024 + lg * 256 + (col & 15) * 16);
            }
            #pragma unroll
            for (int m = 0; m < 4; ++m)
                #pragma unroll
                for (int n = 0; n < 4; ++n)
                    acc[m][n] = MFMA16_(A[m], B[n], acc[m][n]);
        }
    }

    // ---- epilogue: +bias, min over wave's 64 couts, shfl, cross-waveM via pmin
    {
        float pm[4] = {1e30f, 1e30f, 1e30f, 1e30f};
        #pragma unroll
        for (int m = 0; m < 4; ++m) {
            #pragma unroll
            for (int r = 0; r < 4; ++r) {
                float bv = bias[mb + m * 16 + lg * 4 + r];
                #pragma unroll
                for (int n = 0; n < 4; ++n)
                    pm[n] = fminf(pm[n], acc[m][n][r] + bv);
            }
        }
        #pragma unroll
        for (int n = 0; n < 4; ++n) {
            pm[n] = fminf(pm[n], __shfl_xor(pm[n], 16, 64));
            pm[n] = fminf(pm[n], __shfl_xor(pm[n], 32, 64));
        }
        if (lg == 0) {
            #pragma unroll
            for (int n = 0; n < 4; ++n)
                pmin[waveM * 128 + waveC * 64 + n * 16 + l15] = pm[n];
        }
    }
    __syncthreads();
    if (tid < WO) {
        float v = fminf(pmin[tid], pmin[128 + tid]);
        v = tanhf(tanhf(v));
        out[((size_t)b * HO + R) * WO + tid] = v;
    }
}

extern "C" void kernel_launch(void* const* d_in, const int* in_sizes, int n_in,
                              void* d_out, int out_size, void* d_ws, size_t ws_size,
                              hipStream_t stream) {
    const float* x    = (const float*)d_in[0];
    const float* w    = (const float*)d_in[1];
    const float* bias = (const float*)d_in[2];
    float* out = (float*)d_out;

    const size_t ws_needed = (size_t)18 * 4 * 128 * 16;   // 147456 B
    if (ws_size >= ws_needed) {
        unsigned short* wsb = (unsigned short*)d_ws;
        wreorder_3556<<<288, 256, 0, stream>>>(w, wsb);
        conv_min_tanh_3556<true><<<NB * HO, 256, 0, stream>>>(x, w, bias, (const unsigned char*)wsb, out);
    } else {
        conv_min_tanh_3556<false><<<NB * HO, 256, 0, stream>>>(x, w, bias, nullptr, out);
    }
}

// Round 24
// 75.128 us; speedup vs baseline: 1.0168x; 1.0168x over previous
//
#include <hip/hip_runtime.h>
#include <hip/hip_bf16.h>

#define CIN  64
#define HH   128
#define WW   128
#define COUT 128
#define HO   126
#define WO   126
#define NB   32
#define HW   (HH * WW)

typedef __bf16 bf16x8 __attribute__((ext_vector_type(8)));
typedef float f32x4 __attribute__((ext_vector_type(4)));

// ws2 granule layout: [step(18)=(s,h)][kg(4)][cout(128)] 16B granules
// granule(step,kg,cout)[j] = bf16(w[cout][ci = 32h + 8kg + j][s])
__global__ void wreorder_3556(const float* __restrict__ w, unsigned short* __restrict__ ws2) {
    int e = blockIdx.x * 256 + threadIdx.x;      // 0..73727
    if (e >= 73728) return;
    int j = e & 7, cout = (e >> 3) & 127, kg = (e >> 10) & 3, h = (e >> 12) & 1, s = e >> 13;
    __bf16 v = (__bf16)w[cout * 576 + (h * 32 + kg * 8 + j) * 9 + s];
    ws2[e] = __builtin_bit_cast(unsigned short, v);
}

// LDS x layout: [row(3)][h(2)][blk(8)][kg(4)][c(16)] 16B granules, contiguous (no pad)
//   addr(row,h,col,kg) = row*16384 + h*8192 + (col>>4)*1024 + kg*256 + (col&15)*16
// Carry reads (col>=128) land in adjacent region/pmin: garbage -> only discarded cols 126/127.
#define ROW_STRIDE 16384
#define H_STRIDE   8192
#define PM_OFF     49152
#define SMEM_BYTES (49152 + 1024)   // 50176 -> LDS allows 3 blocks/CU

__device__ __forceinline__ unsigned lds_addr(const void* p) {
    return (unsigned)(unsigned long long)(const __attribute__((address_space(3))) unsigned char*)p;
}
template<int OFF>
__device__ __forceinline__ bf16x8 ds_read128(unsigned base) {
    bf16x8 d;
    asm volatile("ds_read_b128 %0, %1 offset:%c2" : "=v"(d) : "v"(base), "i"(OFF));
    return d;
}
template<int OFF>
__device__ __forceinline__ bf16x8 glob_load128(const unsigned char* sbase, unsigned voff) {
    bf16x8 d;
    asm volatile("global_load_dwordx4 %0, %1, %2 offset:%c3"
                 : "=v"(d) : "v"(voff), "s"(sbase), "i"(OFF));
    return d;
}

#define MFMA16_(a, b, c) __builtin_amdgcn_mfma_f32_16x16x32_bf16((a), (b), (c), 0, 0, 0)
#define SBAR() __builtin_amdgcn_sched_barrier(0)

// step T: s = T>>1, h = T&1; kh = s/3, kw = s%3
#define S_(T)  ((T) >> 1)
#define H_(T)  ((T) & 1)
#define KH_(T) (S_(T) / 3)
#define KW_(T) (S_(T) % 3)
#define IMMB(T, N) (KH_(T) * ROW_STRIDE + H_(T) * H_STRIDE + (N) * 1024)

template<bool USE_WS>
__global__ __launch_bounds__(256, 2)   // cap 256 VGPR: keep the pipeline resident (R23's (256,3) collapsed it)
void conv_min_tanh_3556(const float* __restrict__ x, const float* __restrict__ w,
                        const float* __restrict__ bias,
                        const unsigned char* __restrict__ wsr_b,
                        float* __restrict__ out) {
    __shared__ __align__(16) unsigned char smem[SMEM_BYTES];
    float* pmin = (float*)(smem + PM_OFF);

    // XCD-chunked bijective swizzle (4032 = 8 * 504)
    const int bid = blockIdx.x;
    const int blk = (bid & 7) * 504 + (bid >> 3);
    const int b   = blk / HO;
    const int R   = blk - b * HO;            // output row; input rows R..R+2 (always in-bounds)

    const int tid  = threadIdx.x;
    const int lane = tid & 63;
    const int wid  = tid >> 6;               // 0..3
    const int l15 = lane & 15;
    const int lg  = lane >> 4;               // 0..3 (16-lane group)
    const int waveM = wid & 1;               // cout half (0/1)
    const int waveC = wid >> 1;              // col half (0/1)
    const int mb = waveM * 64;

    // ---- A register pipeline + early prefetch (hidden under staging)
    bf16x8 A2[2][4];   // [slot][m]  32 VGPR
    bf16x8 B2[2][4];   // [slot][n]  32 VGPR
    const unsigned voffA = (unsigned)(lg * 2048 + (mb + l15) * 16);

    #define PRELA(T) do { const unsigned _va = voffA + (T) * 8192u;                       \
        A2[(T) & 1][0] = glob_load128<0>(wsr_b, _va);                                     \
        A2[(T) & 1][1] = glob_load128<256>(wsr_b, _va);                                   \
        A2[(T) & 1][2] = glob_load128<512>(wsr_b, _va);                                   \
        A2[(T) & 1][3] = glob_load128<768>(wsr_b, _va); } while (0)

    if constexpr (USE_WS) { PRELA(0); PRELA(1); }

    // ---- stage x rows R..R+2 (768 items, 3/thread), vectorized f32x4, block-16-col layout
    {
        const float* xb = x + (size_t)b * CIN * HW + (size_t)R * WW;
        #pragma unroll
        for (int it = 0; it < 3; ++it) {
            int item = it * 256 + tid;          // 0..767
            int col4 = item & 31;               // 4-col group
            int cg   = (item >> 5) & 7;         // h = cg>>2, kg = cg&3
            int row  = item >> 8;               // 0..2
            const float* src = xb + (size_t)(cg * 8) * HW + (size_t)row * WW + col4 * 4;
            f32x4 v[8];
            #pragma unroll
            for (int j = 0; j < 8; ++j) v[j] = *(const f32x4*)(src + (size_t)j * HW);
            const int wb0 = row * ROW_STRIDE + (cg >> 2) * H_STRIDE + (cg & 3) * 256;
            #pragma unroll
            for (int c = 0; c < 4; ++c) {
                int col = col4 * 4 + c;
                union { unsigned short us[8]; int4 i4; } p;
                #pragma unroll
                for (int j = 0; j < 8; ++j) {
                    __bf16 t = (__bf16)v[j][c];
                    p.us[j] = __builtin_bit_cast(unsigned short, t);
                }
                *(int4*)(smem + wb0 + (col >> 4) * 1024 + (col & 15) * 16) = p.i4;
            }
        }
    }
    __syncthreads();   // drains vmcnt: A2 slots 0,1 resident; xs ready

    f32x4 acc[4][4] = {};   // [m][n] : 64 cout x 64 col, 16x16 tiles

    if constexpr (USE_WS) {
        // B bases per kw: col' = waveC*64 + l15 + kw (waveC*4 blocks folded into base)
        unsigned baseB[3];
        #pragma unroll
        for (int kw = 0; kw < 3; ++kw) {
            int cp = l15 + kw;
            baseB[kw] = lds_addr(smem) + (unsigned)(waveC * 4096 + lg * 256 +
                        (cp >> 4) * 1024 + (cp & 15) * 16);
        }

        // reload one n-pair of B for step T (2 ds_reads into slot T&1)
        #define PRELB2(T, P) do { const unsigned _bb = baseB[KW_(T)];                     \
            B2[(T) & 1][2*(P)]   = ds_read128<IMMB(T, 2*(P))>(_bb);                       \
            B2[(T) & 1][2*(P)+1] = ds_read128<IMMB(T, 2*(P)+1)>(_bb); } while (0)

        // 8 MFMAs: n-pair P across all 4 m — consumes B2[q][2P..2P+1]
        #define MF_NPAIR(Q, P) do {                                                       \
            _Pragma("unroll")                                                             \
            for (int _m = 0; _m < 4; ++_m) {                                              \
                acc[_m][2*(P)]   = MFMA16_(A2[Q][_m], B2[Q][2*(P)],   acc[_m][2*(P)]);    \
                acc[_m][2*(P)+1] = MFMA16_(A2[Q][_m], B2[Q][2*(P)+1], acc[_m][2*(P)+1]);  \
            } } while (0)

        // Interleaved step: {8 MFMA}{2 ds}{8 MFMA}{2 ds + 4 glob}
        #define KSTEP(T) do {                                                             \
            if ((T) <= 16) asm volatile("s_waitcnt lgkmcnt(4) vmcnt(4)" ::: "memory");    \
            else           asm volatile("s_waitcnt lgkmcnt(0) vmcnt(0)" ::: "memory");    \
            SBAR();                                                                       \
            __builtin_amdgcn_s_setprio(1);                                                \
            { const int _q = (T) & 1;                                                     \
              MF_NPAIR(_q, 0); SBAR();                                                    \
              if ((T) + 2 <= 17) { PRELB2((T) + 2, 0); } SBAR();                          \
              MF_NPAIR(_q, 1); SBAR();                                                    \
              if ((T) + 2 <= 17) { PRELB2((T) + 2, 1); PRELA((T) + 2); } }                \
            __builtin_amdgcn_s_setprio(0);                                                \
            SBAR();                                                                       \
        } while (0)

        #define PRELB_ALL(T) do { PRELB2(T,0); PRELB2(T,1); } while (0)
        PRELB_ALL(0); PRELB_ALL(1);

        KSTEP(0);  KSTEP(1);  KSTEP(2);  KSTEP(3);  KSTEP(4);  KSTEP(5);
        KSTEP(6);  KSTEP(7);  KSTEP(8);  KSTEP(9);  KSTEP(10); KSTEP(11);
        KSTEP(12); KSTEP(13); KSTEP(14); KSTEP(15); KSTEP(16); KSTEP(17);

        asm volatile("s_waitcnt lgkmcnt(0) vmcnt(0)" ::: "memory");
        SBAR();
    } else {
        // fallback: plain 18-step loop straight from w
        #pragma unroll
        for (int step = 0; step < 18; ++step) {
            const int s = step >> 1, h = step & 1;
            const int kh = s / 3, kw = s % 3;
            bf16x8 A[4], B[4];
            #pragma unroll
            for (int m = 0; m < 4; ++m)
                #pragma unroll
                for (int j = 0; j < 8; ++j)
                    A[m][j] = (__bf16)w[(mb + m * 16 + l15) * 576 +
                                        (h * 32 + lg * 8 + j) * 9 + s];
            #pragma unroll
            for (int n = 0; n < 4; ++n) {
                int col = waveC * 64 + n * 16 + l15 + kw;
                B[n] = *(const bf16x8*)(smem + kh * ROW_STRIDE + h * H_STRIDE +
                                        (col >> 4) * 1024 + lg * 256 + (col & 15) * 16);
            }
            #pragma unroll
            for (int m = 0; m < 4; ++m)
                #pragma unroll
                for (int n = 0; n < 4; ++n)
                    acc[m][n] = MFMA16_(A[m], B[n], acc[m][n]);
        }
    }

    // ---- epilogue: +bias, min over wave's 64 couts, shfl, cross-waveM via pmin
    {
        float pm[4] = {1e30f, 1e30f, 1e30f, 1e30f};
        #pragma unroll
        for (int m = 0; m < 4; ++m) {
            #pragma unroll
            for (int r = 0; r < 4; ++r) {
                float bv = bias[mb + m * 16 + lg * 4 + r];
                #pragma unroll
                for (int n = 0; n < 4; ++n)
                    pm[n] = fminf(pm[n], acc[m][n][r] + bv);
            }
        }
        #pragma unroll
        for (int n = 0; n < 4; ++n) {
            pm[n] = fminf(pm[n], __shfl_xor(pm[n], 16, 64));
            pm[n] = fminf(pm[n], __shfl_xor(pm[n], 32, 64));
        }
        if (lg == 0) {
            #pragma unroll
            for (int n = 0; n < 4; ++n)
                pmin[waveM * 128 + waveC * 64 + n * 16 + l15] = pm[n];
        }
    }
    __syncthreads();
    if (tid < WO) {
        float v = fminf(pmin[tid], pmin[128 + tid]);
        v = tanhf(tanhf(v));
        out[((size_t)b * HO + R) * WO + tid] = v;
    }
}

extern "C" void kernel_launch(void* const* d_in, const int* in_sizes, int n_in,
                              void* d_out, int out_size, void* d_ws, size_t ws_size,
                              hipStream_t stream) {
    const float* x    = (const float*)d_in[0];
    const float* w    = (const float*)d_in[1];
    const float* bias = (const float*)d_in[2];
    float* out = (float*)d_out;

    const size_t ws_needed = (size_t)18 * 4 * 128 * 16;   // 147456 B
    if (ws_size >= ws_needed) {
        unsigned short* wsb = (unsigned short*)d_ws;
        wreorder_3556<<<288, 256, 0, stream>>>(w, wsb);
        conv_min_tanh_3556<true><<<NB * HO, 256, 0, stream>>>(x, w, bias, (const unsigned char*)wsb, out);
    } else {
        conv_min_tanh_3556<false><<<NB * HO, 256, 0, stream>>>(x, w, bias, nullptr, out);
    }
}